// Round 5
// baseline (117.065 us; speedup 1.0000x reference)
//
#include <hip/hip_runtime.h>
#include <math.h>

#define B_BAGS 512
#define N_REL  128
#define D_DIM  768

typedef __attribute__((ext_vector_type(8))) short  bf16x8;
typedef __attribute__((ext_vector_type(4))) float  f32x4;

// pack truncated-bf16 of (f0,f1) -> one uint (low short = bf16(f0))
__device__ inline unsigned pack_hi(float f0, float f1) {
    return __builtin_amdgcn_perm(__float_as_uint(f1), __float_as_uint(f0), 0x07060302u);
}
__device__ inline float trunc_res(float f) {   // f - bf16_trunc(f)
    return f - __uint_as_float(__float_as_uint(f) & 0xFFFF0000u);
}

// ---------------------------------------------------------------------------
// K1: fragment-ordered bf16 hi/lo of W for the MFMA B-operand (validated r2-r4).
// Element = W[n][k], n = tile*16 + (lane&15), k = s*32 + (lane>>4)*8 + j.
// ---------------------------------------------------------------------------
__global__ void build_bfrag(const float* __restrict__ W, unsigned* __restrict__ Bfrag) {
    int flat = blockIdx.x * 256 + threadIdx.x;     // 0..12287
    int lane = flat & 63;
    int tile = (flat >> 6) & 7;
    int s    = flat >> 9;                          // 0..23
    int n  = tile * 16 + (lane & 15);
    int k0 = s * 32 + (lane >> 4) * 8;
    const float* src = &W[n * D_DIM + k0];
    float f[8];
    #pragma unroll
    for (int j = 0; j < 8; ++j) f[j] = src[j];
    unsigned hi[4], lo[4];
    #pragma unroll
    for (int q = 0; q < 4; ++q) {
        hi[q] = pack_hi(f[2*q], f[2*q+1]);
        lo[q] = pack_hi(trunc_res(f[2*q]), trunc_res(f[2*q+1]));
    }
    unsigned base = (unsigned)(((s * 8 + tile) * 2) * 64 + lane) * 4;
    *(uint4*)&Bfrag[base]          = make_uint4(hi[0], hi[1], hi[2], hi[3]);
    *(uint4*)&Bfrag[base + 64 * 4] = make_uint4(lo[0], lo[1], lo[2], lo[3]);
}

// ---------------------------------------------------------------------------
// K2: fully fused per-bag kernel. One barrier total.
//  Phase 1: G = bag @ W^T (bf16x3 MFMA, A from global per validated h_gemm
//           fragment pattern, B from Bfrag). Wave wv owns n-tiles {2wv,2wv+1},
//           both m-tiles (m 0..31; rows >= size are masked later).
//  Softmax over m: in-register on C/D layout (shuffle xor 16/32), then G and
//           SM scattered from registers into r4-validated frag layouts in LDS.
//  Phase 2: full = SM @ G (r4-validated 48-MFMA pattern), row softmax over k
//           in-register (shuffle xor 1/2/4/8), diagonal -> out.
// ---------------------------------------------------------------------------
__global__ __launch_bounds__(256, 2) void bag_fused(
    const float*          __restrict__ rep,    // nsum x 768
    const unsigned short* __restrict__ Bfrag,  // fragment-ordered W hi/lo
    const float*          __restrict__ bias,   // 128
    const int*            __restrict__ scope,  // B x 2
    float*                __restrict__ out,    // B x 128
    int nsum)
{
    __shared__ unsigned Gfrag[8 * 2 * 64 * 4];    // 16 KB: [tile][p][lane][4]
    __shared__ unsigned SMfrag[8 * 2 * 64 * 4];   // 16 KB: same layout

    const int t = threadIdx.x;
    const int b = blockIdx.x;
    const int start = scope[2 * b];
    const int size  = scope[2 * b + 1] - start;   // in [8, 25)

    const int wv   = t >> 6;
    const int lane = t & 63;
    const int nl15 = lane & 15;
    const int lg   = lane >> 4;

    // bias for phase 2: bias_r[ct] = bias[ct*16 + nl15] (k = ct*16 + lane&15)
    float bias_r[8];
    #pragma unroll
    for (int ct = 0; ct < 8; ++ct) bias_r[ct] = bias[ct * 16 + nl15];

    // ---- Phase 1: A-fragment pointers (validated h_gemm pattern) ----
    const float* rpA[2];
    #pragma unroll
    for (int mt = 0; mt < 2; ++mt) {
        int row = start + mt * 16 + nl15;
        row = (row > nsum - 1) ? (nsum - 1) : row;   // clip like reference
        rpA[mt] = &rep[(size_t)row * D_DIM + lg * 8];
    }

    f32x4 acc[2][2][2];   // [mt][ntl][0]=hi*hi, [1]=hi*lo + lo*hi
    #pragma unroll
    for (int mt = 0; mt < 2; ++mt)
        #pragma unroll
        for (int ntl = 0; ntl < 2; ++ntl) {
            acc[mt][ntl][0] = f32x4{0.f, 0.f, 0.f, 0.f};
            acc[mt][ntl][1] = f32x4{0.f, 0.f, 0.f, 0.f};
        }

    #pragma unroll 4
    for (int gs = 0; gs < 24; ++gs) {
        union { unsigned u[4]; bf16x8 v; } ah[2], al[2];
        #pragma unroll
        for (int mt = 0; mt < 2; ++mt) {
            const float4 v0 = *(const float4*)&rpA[mt][gs * 32];
            const float4 v1 = *(const float4*)&rpA[mt][gs * 32 + 4];
            ah[mt].u[0] = pack_hi(v0.x, v0.y);
            ah[mt].u[1] = pack_hi(v0.z, v0.w);
            ah[mt].u[2] = pack_hi(v1.x, v1.y);
            ah[mt].u[3] = pack_hi(v1.z, v1.w);
            al[mt].u[0] = pack_hi(trunc_res(v0.x), trunc_res(v0.y));
            al[mt].u[1] = pack_hi(trunc_res(v0.z), trunc_res(v0.w));
            al[mt].u[2] = pack_hi(trunc_res(v1.x), trunc_res(v1.y));
            al[mt].u[3] = pack_hi(trunc_res(v1.z), trunc_res(v1.w));
        }
        #pragma unroll
        for (int ntl = 0; ntl < 2; ++ntl) {
            const int tid8 = gs * 8 + wv * 2 + ntl;
            const bf16x8 bh = *(const bf16x8*)&Bfrag[((size_t)(tid8 * 2 + 0) * 64 + lane) * 8];
            const bf16x8 bl = *(const bf16x8*)&Bfrag[((size_t)(tid8 * 2 + 1) * 64 + lane) * 8];
            #pragma unroll
            for (int mt = 0; mt < 2; ++mt) {
                acc[mt][ntl][0] = __builtin_amdgcn_mfma_f32_16x16x32_bf16(ah[mt].v, bh, acc[mt][ntl][0], 0, 0, 0);
                acc[mt][ntl][1] = __builtin_amdgcn_mfma_f32_16x16x32_bf16(ah[mt].v, bl, acc[mt][ntl][1], 0, 0, 0);
                acc[mt][ntl][1] = __builtin_amdgcn_mfma_f32_16x16x32_bf16(al[mt].v, bh, acc[mt][ntl][1], 0, 0, 0);
            }
        }
    }

    // ---- in-register masked softmax over m + scatter to frag layouts ----
    // C/D layout (validated): row m_local = lg*4 + r, col n_local = nl15.
    #pragma unroll
    for (int ntl = 0; ntl < 2; ++ntl) {
        const int T = wv * 2 + ntl;                // n-tile == phase-2 row-tile
        float gv[2][4], smv[2][4];
        #pragma unroll
        for (int mt = 0; mt < 2; ++mt)
            #pragma unroll
            for (int r = 0; r < 4; ++r)
                gv[mt][r] = acc[mt][ntl][0][r] + acc[mt][ntl][1][r];

        float vmax = -INFINITY;
        #pragma unroll
        for (int mt = 0; mt < 2; ++mt)
            #pragma unroll
            for (int r = 0; r < 4; ++r) {
                const int m = mt * 16 + lg * 4 + r;
                if (m < size) vmax = fmaxf(vmax, gv[mt][r]);
            }
        vmax = fmaxf(vmax, __shfl_xor(vmax, 16));
        vmax = fmaxf(vmax, __shfl_xor(vmax, 32));

        float ssum = 0.f;
        #pragma unroll
        for (int mt = 0; mt < 2; ++mt)
            #pragma unroll
            for (int r = 0; r < 4; ++r) {
                const int m = mt * 16 + lg * 4 + r;
                float e = (m < size) ? __expf(gv[mt][r] - vmax) : 0.f;
                smv[mt][r] = e;
                ssum += e;
            }
        ssum += __shfl_xor(ssum, 16);
        ssum += __shfl_xor(ssum, 32);
        const float inv = 1.f / ssum;
        #pragma unroll
        for (int mt = 0; mt < 2; ++mt)
            #pragma unroll
            for (int r = 0; r < 4; ++r) smv[mt][r] *= inv;

        // scatter pairs (m, m+1) = adjacent regs into r4-validated layouts:
        // uint index = ((T*2 + p)*64 + (m>>3)*16 + nl15)*4 + ((m>>1)&3)
        #pragma unroll
        for (int mt = 0; mt < 2; ++mt)
            #pragma unroll
            for (int rp = 0; rp < 4; rp += 2) {
                const int m     = mt * 16 + lg * 4 + rp;
                const int lane2 = (m >> 3) * 16 + nl15;
                const int word  = (m >> 1) & 3;
                const int ihi = ((T * 2 + 0) * 64 + lane2) * 4 + word;
                const int ilo = ((T * 2 + 1) * 64 + lane2) * 4 + word;
                Gfrag[ihi]  = pack_hi(gv[mt][rp], gv[mt][rp + 1]);
                Gfrag[ilo]  = pack_hi(trunc_res(gv[mt][rp]), trunc_res(gv[mt][rp + 1]));
                SMfrag[ihi] = pack_hi(smv[mt][rp], smv[mt][rp + 1]);
                SMfrag[ilo] = pack_hi(trunc_res(smv[mt][rp]), trunc_res(smv[mt][rp + 1]));
            }
    }
    __syncthreads();   // the only barrier

    // ---- Phase 2: full = SM @ G (r4-validated wiring) ----
    f32x4 facc[2][8];
    #pragma unroll
    for (int tt = 0; tt < 2; ++tt)
        #pragma unroll
        for (int ct = 0; ct < 8; ++ct)
            facc[tt][ct] = f32x4{0.f, 0.f, 0.f, 0.f};

    bf16x8 ah2[2], al2[2];
    #pragma unroll
    for (int tt = 0; tt < 2; ++tt) {
        const int T = wv * 2 + tt;
        ah2[tt] = *(const bf16x8*)&SMfrag[((T * 2 + 0) * 64 + lane) * 4];
        al2[tt] = *(const bf16x8*)&SMfrag[((T * 2 + 1) * 64 + lane) * 4];
    }
    #pragma unroll
    for (int ct = 0; ct < 8; ++ct) {
        const bf16x8 bh = *(const bf16x8*)&Gfrag[((ct * 2 + 0) * 64 + lane) * 4];
        const bf16x8 bl = *(const bf16x8*)&Gfrag[((ct * 2 + 1) * 64 + lane) * 4];
        #pragma unroll
        for (int tt = 0; tt < 2; ++tt) {
            facc[tt][ct] = __builtin_amdgcn_mfma_f32_16x16x32_bf16(ah2[tt], bh, facc[tt][ct], 0, 0, 0);
            facc[tt][ct] = __builtin_amdgcn_mfma_f32_16x16x32_bf16(ah2[tt], bl, facc[tt][ct], 0, 0, 0);
            facc[tt][ct] = __builtin_amdgcn_mfma_f32_16x16x32_bf16(al2[tt], bh, facc[tt][ct], 0, 0, 0);
        }
    }

    // ---- in-register row softmax over k + diagonal -> out ----
    // C/D layout: row n_local = lg*4 + r, col k = ct*16 + nl15.
    #pragma unroll
    for (int tt = 0; tt < 2; ++tt) {
        const int T = wv * 2 + tt;
        #pragma unroll
        for (int r = 0; r < 4; ++r) {
            float s[8];
            #pragma unroll
            for (int ct = 0; ct < 8; ++ct) s[ct] = facc[tt][ct][r] + bias_r[ct];

            float mx = s[0];
            #pragma unroll
            for (int ct = 1; ct < 8; ++ct) mx = fmaxf(mx, s[ct]);
            mx = fmaxf(mx, __shfl_xor(mx, 1));
            mx = fmaxf(mx, __shfl_xor(mx, 2));
            mx = fmaxf(mx, __shfl_xor(mx, 4));
            mx = fmaxf(mx, __shfl_xor(mx, 8));

            float l = 0.f;
            #pragma unroll
            for (int ct = 0; ct < 8; ++ct) l += __expf(s[ct] - mx);
            l += __shfl_xor(l, 1);
            l += __shfl_xor(l, 2);
            l += __shfl_xor(l, 4);
            l += __shfl_xor(l, 8);

            const int nl = lg * 4 + r;                // row within tile
            // diag element k == n lives at ct == T on the lane with nl15 == nl
            float sd = s[0];
            #pragma unroll
            for (int ct = 1; ct < 8; ++ct) sd = (ct == T) ? s[ct] : sd;
            if (nl15 == nl) {
                const int n = T * 16 + nl;
                out[b * N_REL + n] = __expf(sd - mx) / l;
            }
        }
    }
}

// ---------------------------------------------------------------------------
extern "C" void kernel_launch(void* const* d_in, const int* in_sizes, int n_in,
                              void* d_out, int out_size, void* d_ws, size_t ws_size,
                              hipStream_t stream) {
    const float* rep   = (const float*)d_in[0];
    const float* W     = (const float*)d_in[1];
    const float* bias  = (const float*)d_in[2];
    const int*   scope = (const int*)d_in[3];

    const int nsum = in_sizes[0] / D_DIM;
    unsigned* Bfrag = (unsigned*)d_ws;   // 393216 B

    build_bfrag<<<48, 256, 0, stream>>>(W, Bfrag);
    bag_fused<<<B_BAGS, 256, 0, stream>>>(rep, (const unsigned short*)Bfrag,
                                          bias, scope, (float*)d_out, nsum);
}

// Round 6
// 104.140 us; speedup vs baseline: 1.1241x; 1.1241x over previous
//
#include <hip/hip_runtime.h>
#include <math.h>

#define B_BAGS 512
#define N_REL  128
#define D_DIM  768

typedef __attribute__((ext_vector_type(8))) short  bf16x8;
typedef __attribute__((ext_vector_type(4))) float  f32x4;

// pack truncated-bf16 of (f0,f1) -> one uint (low short = bf16(f0))
__device__ inline unsigned pack_hi(float f0, float f1) {
    return __builtin_amdgcn_perm(__float_as_uint(f1), __float_as_uint(f0), 0x07060302u);
}
__device__ inline float trunc_res(float f) {   // f - bf16_trunc(f)
    return f - __uint_as_float(__float_as_uint(f) & 0xFFFF0000u);
}

// ---------------------------------------------------------------------------
// K1: fragment-ordered bf16 hi/lo of W for the MFMA B-operand (validated r2-r5).
// Element = W[n][k], n = tile*16 + (lane&15), k = s*32 + (lane>>4)*8 + j.
// ---------------------------------------------------------------------------
__global__ void build_bfrag(const float* __restrict__ W, unsigned* __restrict__ Bfrag) {
    int flat = blockIdx.x * 256 + threadIdx.x;     // 0..12287
    int lane = flat & 63;
    int tile = (flat >> 6) & 7;
    int s    = flat >> 9;                          // 0..23
    int n  = tile * 16 + (lane & 15);
    int k0 = s * 32 + (lane >> 4) * 8;
    const float* src = &W[n * D_DIM + k0];
    float f[8];
    #pragma unroll
    for (int j = 0; j < 8; ++j) f[j] = src[j];
    unsigned hi[4], lo[4];
    #pragma unroll
    for (int q = 0; q < 4; ++q) {
        hi[q] = pack_hi(f[2*q], f[2*q+1]);
        lo[q] = pack_hi(trunc_res(f[2*q]), trunc_res(f[2*q+1]));
    }
    unsigned base = (unsigned)(((s * 8 + tile) * 2) * 64 + lane) * 4;
    *(uint4*)&Bfrag[base]          = make_uint4(hi[0], hi[1], hi[2], hi[3]);
    *(uint4*)&Bfrag[base + 64 * 4] = make_uint4(lo[0], lo[1], lo[2], lo[3]);
}

// ---------------------------------------------------------------------------
// K2: fused per-bag kernel, 8 waves/block, K-split phase 1, register-pipelined.
//  Phase 1: wave (h = wv>>2, q = wv&3) computes K-half h of n-tiles {2q,2q+1}
//           (bf16x3 MFMA, A from global, B from Bfrag), with explicit s+1
//           register prefetch. Partials summed via LDS Gpart.
//  Softmax over m: wave T=wv owns n-tile T; in-register (shuffle xor 16/32),
//           scatter G/SM to r4/r5-validated frag layouts.
//  Phase 2: wave T computes row-tile T of full = SM@G (24 MFMA), row softmax
//           over k in-register (xor 1/2/4/8), diagonal -> out.
// ---------------------------------------------------------------------------
__global__ __launch_bounds__(512, 4) void bag_fused(
    const float*          __restrict__ rep,    // nsum x 768
    const unsigned short* __restrict__ Bfrag,  // fragment-ordered W hi/lo
    const float*          __restrict__ bias,   // 128
    const int*            __restrict__ scope,  // B x 2
    float*                __restrict__ out,    // B x 128
    int nsum)
{
    __shared__ f32x4    Gpart[2][2][8][64];       // [h][mt][nt][lane]  32 KB
    __shared__ unsigned Gfrag[8 * 2 * 64 * 4];    // 16 KB [tile][p][lane][4]
    __shared__ unsigned SMfrag[8 * 2 * 64 * 4];   // 16 KB

    const int t = threadIdx.x;
    const int b = blockIdx.x;
    const int start = scope[2 * b];
    const int size  = scope[2 * b + 1] - start;   // in [8, 25)

    const int wv   = t >> 6;
    const int lane = t & 63;
    const int nl15 = lane & 15;
    const int lg   = lane >> 4;
    const int h    = wv >> 2;    // K-half (0: k<384, 1: k>=384)
    const int q    = wv & 3;     // n-tile pair {2q, 2q+1}

    // ---- Phase 1: A pointers (validated pattern), offset to this K-half ----
    const float* rpA[2];
    #pragma unroll
    for (int mt = 0; mt < 2; ++mt) {
        int row = start + mt * 16 + nl15;
        row = (row > nsum - 1) ? (nsum - 1) : row;
        rpA[mt] = &rep[(size_t)row * D_DIM + h * 384 + lg * 8];
    }

    f32x4 acc[2][2][2];   // [mt][ntl][0]=hi*hi, [1]=hi*lo+lo*hi
    #pragma unroll
    for (int mt = 0; mt < 2; ++mt)
        #pragma unroll
        for (int ntl = 0; ntl < 2; ++ntl) {
            acc[mt][ntl][0] = f32x4{0.f, 0.f, 0.f, 0.f};
            acc[mt][ntl][1] = f32x4{0.f, 0.f, 0.f, 0.f};
        }

    // register double-buffered pipeline over 12 K-steps
    float4 cr[2][2];        // current rep quads [mt][half]
    uint4  cbh[2], cbl[2];  // current B frags  [ntl]
    #pragma unroll
    for (int mt = 0; mt < 2; ++mt) {
        cr[mt][0] = *(const float4*)&rpA[mt][0];
        cr[mt][1] = *(const float4*)&rpA[mt][4];
    }
    #pragma unroll
    for (int ntl = 0; ntl < 2; ++ntl) {
        const int tid8 = (h * 12) * 8 + q * 2 + ntl;
        cbh[ntl] = *(const uint4*)&Bfrag[((size_t)(tid8 * 2 + 0) * 64 + lane) * 8];
        cbl[ntl] = *(const uint4*)&Bfrag[((size_t)(tid8 * 2 + 1) * 64 + lane) * 8];
    }

    #pragma unroll
    for (int s = 0; s < 12; ++s) {
        float4 nr[2][2];
        uint4  nbh[2], nbl[2];
        if (s < 11) {   // prefetch s+1 (compile-time guard, fully unrolled)
            #pragma unroll
            for (int mt = 0; mt < 2; ++mt) {
                nr[mt][0] = *(const float4*)&rpA[mt][(s + 1) * 32];
                nr[mt][1] = *(const float4*)&rpA[mt][(s + 1) * 32 + 4];
            }
            #pragma unroll
            for (int ntl = 0; ntl < 2; ++ntl) {
                const int tid8 = (h * 12 + s + 1) * 8 + q * 2 + ntl;
                nbh[ntl] = *(const uint4*)&Bfrag[((size_t)(tid8 * 2 + 0) * 64 + lane) * 8];
                nbl[ntl] = *(const uint4*)&Bfrag[((size_t)(tid8 * 2 + 1) * 64 + lane) * 8];
            }
        }

        union { unsigned u[4]; bf16x8 v; } ah[2], al[2];
        #pragma unroll
        for (int mt = 0; mt < 2; ++mt) {
            const float4 v0 = cr[mt][0];
            const float4 v1 = cr[mt][1];
            ah[mt].u[0] = pack_hi(v0.x, v0.y);
            ah[mt].u[1] = pack_hi(v0.z, v0.w);
            ah[mt].u[2] = pack_hi(v1.x, v1.y);
            ah[mt].u[3] = pack_hi(v1.z, v1.w);
            al[mt].u[0] = pack_hi(trunc_res(v0.x), trunc_res(v0.y));
            al[mt].u[1] = pack_hi(trunc_res(v0.z), trunc_res(v0.w));
            al[mt].u[2] = pack_hi(trunc_res(v1.x), trunc_res(v1.y));
            al[mt].u[3] = pack_hi(trunc_res(v1.z), trunc_res(v1.w));
        }
        #pragma unroll
        for (int ntl = 0; ntl < 2; ++ntl) {
            union { uint4 u; bf16x8 v; } bh, bl;
            bh.u = cbh[ntl];
            bl.u = cbl[ntl];
            #pragma unroll
            for (int mt = 0; mt < 2; ++mt) {
                acc[mt][ntl][0] = __builtin_amdgcn_mfma_f32_16x16x32_bf16(ah[mt].v, bh.v, acc[mt][ntl][0], 0, 0, 0);
                acc[mt][ntl][1] = __builtin_amdgcn_mfma_f32_16x16x32_bf16(ah[mt].v, bl.v, acc[mt][ntl][1], 0, 0, 0);
                acc[mt][ntl][1] = __builtin_amdgcn_mfma_f32_16x16x32_bf16(al[mt].v, bh.v, acc[mt][ntl][1], 0, 0, 0);
            }
        }

        if (s < 11) {   // rotate buffers (SSA rename under full unroll)
            #pragma unroll
            for (int mt = 0; mt < 2; ++mt) { cr[mt][0] = nr[mt][0]; cr[mt][1] = nr[mt][1]; }
            #pragma unroll
            for (int ntl = 0; ntl < 2; ++ntl) { cbh[ntl] = nbh[ntl]; cbl[ntl] = nbl[ntl]; }
        }
    }

    // ---- write K-half partials to LDS ----
    #pragma unroll
    for (int mt = 0; mt < 2; ++mt)
        #pragma unroll
        for (int ntl = 0; ntl < 2; ++ntl)
            Gpart[h][mt][q * 2 + ntl][lane] = acc[mt][ntl][0] + acc[mt][ntl][1];
    __syncthreads();

    // ---- in-register masked softmax over m for n-tile T = wv ----
    // C/D layout (validated): row m_local = lg*4 + r, col n_local = nl15.
    const int T = wv;
    float gv[2][4], smv[2][4];
    #pragma unroll
    for (int mt = 0; mt < 2; ++mt) {
        const f32x4 p0 = Gpart[0][mt][T][lane];
        const f32x4 p1 = Gpart[1][mt][T][lane];
        #pragma unroll
        for (int r = 0; r < 4; ++r) gv[mt][r] = p0[r] + p1[r];
    }

    float vmax = -INFINITY;
    #pragma unroll
    for (int mt = 0; mt < 2; ++mt)
        #pragma unroll
        for (int r = 0; r < 4; ++r) {
            const int m = mt * 16 + lg * 4 + r;
            if (m < size) vmax = fmaxf(vmax, gv[mt][r]);
        }
    vmax = fmaxf(vmax, __shfl_xor(vmax, 16));
    vmax = fmaxf(vmax, __shfl_xor(vmax, 32));

    float ssum = 0.f;
    #pragma unroll
    for (int mt = 0; mt < 2; ++mt)
        #pragma unroll
        for (int r = 0; r < 4; ++r) {
            const int m = mt * 16 + lg * 4 + r;
            float e = (m < size) ? __expf(gv[mt][r] - vmax) : 0.f;
            smv[mt][r] = e;
            ssum += e;
        }
    ssum += __shfl_xor(ssum, 16);
    ssum += __shfl_xor(ssum, 32);
    const float inv = 1.f / ssum;
    #pragma unroll
    for (int mt = 0; mt < 2; ++mt)
        #pragma unroll
        for (int r = 0; r < 4; ++r) smv[mt][r] *= inv;

    // scatter pairs (m, m+1) into r4/r5-validated frag layouts:
    // uint index = ((T*2 + p)*64 + (m>>3)*16 + nl15)*4 + ((m>>1)&3)
    #pragma unroll
    for (int mt = 0; mt < 2; ++mt)
        #pragma unroll
        for (int rp = 0; rp < 4; rp += 2) {
            const int m     = mt * 16 + lg * 4 + rp;
            const int lane2 = (m >> 3) * 16 + nl15;
            const int word  = (m >> 1) & 3;
            const int ihi = ((T * 2 + 0) * 64 + lane2) * 4 + word;
            const int ilo = ((T * 2 + 1) * 64 + lane2) * 4 + word;
            Gfrag[ihi]  = pack_hi(gv[mt][rp], gv[mt][rp + 1]);
            Gfrag[ilo]  = pack_hi(trunc_res(gv[mt][rp]), trunc_res(gv[mt][rp + 1]));
            SMfrag[ihi] = pack_hi(smv[mt][rp], smv[mt][rp + 1]);
            SMfrag[ilo] = pack_hi(trunc_res(smv[mt][rp]), trunc_res(smv[mt][rp + 1]));
        }
    __syncthreads();

    // ---- Phase 2: wave T computes row-tile T of full = SM @ G ----
    float bias_r[8];
    #pragma unroll
    for (int ct = 0; ct < 8; ++ct) bias_r[ct] = bias[ct * 16 + nl15];

    f32x4 facc[8];
    #pragma unroll
    for (int ct = 0; ct < 8; ++ct) facc[ct] = f32x4{0.f, 0.f, 0.f, 0.f};

    const bf16x8 ah2 = *(const bf16x8*)&SMfrag[((T * 2 + 0) * 64 + lane) * 4];
    const bf16x8 al2 = *(const bf16x8*)&SMfrag[((T * 2 + 1) * 64 + lane) * 4];
    #pragma unroll
    for (int ct = 0; ct < 8; ++ct) {
        const bf16x8 bh = *(const bf16x8*)&Gfrag[((ct * 2 + 0) * 64 + lane) * 4];
        const bf16x8 bl = *(const bf16x8*)&Gfrag[((ct * 2 + 1) * 64 + lane) * 4];
        facc[ct] = __builtin_amdgcn_mfma_f32_16x16x32_bf16(ah2, bh, facc[ct], 0, 0, 0);
        facc[ct] = __builtin_amdgcn_mfma_f32_16x16x32_bf16(ah2, bl, facc[ct], 0, 0, 0);
        facc[ct] = __builtin_amdgcn_mfma_f32_16x16x32_bf16(al2, bh, facc[ct], 0, 0, 0);
    }

    // ---- in-register row softmax over k + diagonal -> out (r5-validated) ----
    // C/D layout: row n_local = lg*4 + r, col k = ct*16 + nl15.
    #pragma unroll
    for (int r = 0; r < 4; ++r) {
        float s[8];
        #pragma unroll
        for (int ct = 0; ct < 8; ++ct) s[ct] = facc[ct][r] + bias_r[ct];

        float mx = s[0];
        #pragma unroll
        for (int ct = 1; ct < 8; ++ct) mx = fmaxf(mx, s[ct]);
        mx = fmaxf(mx, __shfl_xor(mx, 1));
        mx = fmaxf(mx, __shfl_xor(mx, 2));
        mx = fmaxf(mx, __shfl_xor(mx, 4));
        mx = fmaxf(mx, __shfl_xor(mx, 8));

        float l = 0.f;
        #pragma unroll
        for (int ct = 0; ct < 8; ++ct) l += __expf(s[ct] - mx);
        l += __shfl_xor(l, 1);
        l += __shfl_xor(l, 2);
        l += __shfl_xor(l, 4);
        l += __shfl_xor(l, 8);

        const int nl = lg * 4 + r;               // row within tile
        float sd = s[0];
        #pragma unroll
        for (int ct = 1; ct < 8; ++ct) sd = (ct == T) ? s[ct] : sd;
        if (nl15 == nl) {
            out[b * N_REL + T * 16 + nl] = __expf(sd - mx) / l;
        }
    }
}

// ---------------------------------------------------------------------------
extern "C" void kernel_launch(void* const* d_in, const int* in_sizes, int n_in,
                              void* d_out, int out_size, void* d_ws, size_t ws_size,
                              hipStream_t stream) {
    const float* rep   = (const float*)d_in[0];
    const float* W     = (const float*)d_in[1];
    const float* bias  = (const float*)d_in[2];
    const int*   scope = (const int*)d_in[3];

    const int nsum = in_sizes[0] / D_DIM;
    unsigned* Bfrag = (unsigned*)d_ws;   // 393216 B

    build_bfrag<<<48, 256, 0, stream>>>(W, Bfrag);
    bag_fused<<<B_BAGS, 512, 0, stream>>>(rep, (const unsigned short*)Bfrag,
                                          bias, scope, (float*)d_out, nsum);
}